// Round 6
// baseline (817.243 us; speedup 1.0000x reference)
//
#include <hip/hip_runtime.h>
#include <math.h>

#define RR 3
#define NTOT 100000
#define NN0 80000
#define NN1 20000
#define NB 4096
#define NE1 300000
#define NE2 65536
#define FIN 128
#define HC1 256   // layer1: 2 heads x 128
#define HC2 128   // layer2: 1 head x 128

typedef __attribute__((ext_vector_type(8))) short bf16x8;
typedef __attribute__((ext_vector_type(4))) short s16x4;
typedef __attribute__((ext_vector_type(2))) short s16x2;
typedef __attribute__((ext_vector_type(4))) float f32x4;

__device__ __forceinline__ float wave_red_sum(float v) {
    #pragma unroll
    for (int off = 32; off >= 1; off >>= 1) v += __shfl_xor(v, off, 64);
    return v;
}

__device__ __forceinline__ short f2bf(float x) {
    union { float f; unsigned u; } c; c.f = x;
    unsigned r = c.u + 0x7fffu + ((c.u >> 16) & 1u);
    return (short)(r >> 16);
}
__device__ __forceinline__ float bf2f(short s) {
    union { unsigned u; float f; } c; c.u = ((unsigned)(unsigned short)s) << 16;
    return c.f;
}

__device__ __forceinline__ float4 ld4(const float* p) { return *(const float4*)p; }
__device__ __forceinline__ float4 ld4(const short* p) {
    s16x4 v = *(const s16x4*)p;
    float4 r = { bf2f(v[0]), bf2f(v[1]), bf2f(v[2]), bf2f(v[3]) };
    return r;
}
__device__ __forceinline__ float2 ld2(const float* p) { return *(const float2*)p; }
__device__ __forceinline__ float2 ld2(const short* p) {
    s16x2 v = *(const s16x2*)p;
    float2 r = { bf2f(v[0]), bf2f(v[1]) };
    return r;
}

// ---------- convert features f32 -> bf16 ----------
__global__ void __launch_bounds__(256)
fcvt_k(const float* __restrict__ f, short* __restrict__ o, int n4) {
    int i = blockIdx.x * 256 + threadIdx.x;
    if (i < n4) {
        float4 v = *(const float4*)(f + (size_t)i * 4);
        s16x4 s = { f2bf(v.x), f2bf(v.y), f2bf(v.z), f2bf(v.w) };
        *(s16x4*)(o + (size_t)i * 4) = s;
    }
}

// ---------- pack 4 weight mats per replica into MFMA B-fragment order ----------
template<int K, int N>
__global__ void __launch_bounds__(256)
wpack_k(const float* __restrict__ W0, const float* __restrict__ W1,
        const float* __restrict__ W2, const float* __restrict__ W3,
        short* __restrict__ P) {
    constexpr int KS = K / 32;
    const int m = blockIdx.y, r = blockIdx.z;
    const float* W = (m == 0 ? W0 : m == 1 ? W1 : m == 2 ? W2 : W3) + (size_t)r * K * N;
    short* o = P + ((size_t)(r * 4 + m)) * K * N;
    for (int i = blockIdx.x * 256 + threadIdx.x; i < K * N; i += gridDim.x * 256) {
        int j = i & 7, lane = (i >> 3) & 63, f = i >> 9;
        int ks = f % KS, nt = f / KS;
        int k = ks * 32 + (lane >> 4) * 8 + j;
        int n = nt * 16 + (lane & 15);
        o[i] = f2bf(W[(size_t)k * N + n]);
    }
}

// ---------- MFMA GEMM, low-pressure tiling; per-output row stride (ldo) ----------
template<int K, int N, typename OT0, typename OT1>
__global__ void __launch_bounds__(256)
gemm2l(const short* __restrict__ xbf, int ldx, const int* __restrict__ gidx,
       const short* __restrict__ P0, const float* __restrict__ b0, OT0* __restrict__ out0, int ldo0,
       const short* __restrict__ P1, const float* __restrict__ b1, OT1* __restrict__ out1, int ldo1)
{
    constexpr int NT = N / 16;
    constexpr int NW = NT / 4;
    constexpr int KS = K / 32;
    constexpr int MT = 2;
    const int lane = threadIdx.x & 63;
    const int wid  = threadIdx.x >> 6;
    const int rowbase = blockIdx.x * (MT * 16);

    const short* ap[MT];
    #pragma unroll
    for (int mt = 0; mt < MT; ++mt) {
        int arow = rowbase + mt * 16 + (lane & 15);
        int srow = gidx ? gidx[arow] : arow;
        ap[mt] = xbf + (size_t)srow * ldx + ((lane >> 4) * 8);
    }
    const int fb = lane * 8;

    f32x4 acc[MT][NW][2];
    #pragma unroll
    for (int mt = 0; mt < MT; ++mt)
        #pragma unroll
        for (int j = 0; j < NW; ++j) { acc[mt][j][0] = (f32x4)(0.0f); acc[mt][j][1] = (f32x4)(0.0f); }

    for (int ks = 0; ks < KS; ++ks) {
        bf16x8 a[MT];
        #pragma unroll
        for (int mt = 0; mt < MT; ++mt) a[mt] = *(const bf16x8*)(ap[mt] + ks * 32);
        #pragma unroll
        for (int j = 0; j < NW; ++j) {
            const int nt = wid * NW + j;
            const int off = ((nt * KS + ks) << 9) + fb;
            bf16x8 bv0 = *(const bf16x8*)(P0 + off);
            bf16x8 bv1 = *(const bf16x8*)(P1 + off);
            #pragma unroll
            for (int mt = 0; mt < MT; ++mt) {
                acc[mt][j][0] = __builtin_amdgcn_mfma_f32_16x16x32_bf16(a[mt], bv0, acc[mt][j][0], 0, 0, 0);
                acc[mt][j][1] = __builtin_amdgcn_mfma_f32_16x16x32_bf16(a[mt], bv1, acc[mt][j][1], 0, 0, 0);
            }
        }
    }

    __shared__ float ls[MT * 16][N + 4];
    constexpr int CPT = (MT * 16) * N / 8 / 256;
    const int tid = threadIdx.x;

    #pragma unroll
    for (int mat = 0; mat < 2; ++mat) {
        if (mat) __syncthreads();
        const float* bias = mat ? b1 : b0;
        #pragma unroll
        for (int j = 0; j < NW; ++j) {
            const int nt = wid * NW + j;
            const float bb = bias[nt * 16 + (lane & 15)];
            #pragma unroll
            for (int mt = 0; mt < MT; ++mt)
                #pragma unroll
                for (int rg = 0; rg < 4; ++rg)
                    ls[mt * 16 + (lane >> 4) * 4 + rg][nt * 16 + (lane & 15)] =
                        acc[mt][j][mat][rg] + bb;
        }
        __syncthreads();
        #pragma unroll
        for (int c2 = 0; c2 < CPT; ++c2) {
            const int chunk = c2 * 256 + tid;
            const int row = chunk / (N / 8);
            const int colb = (chunk % (N / 8)) * 8;
            float v[8];
            #pragma unroll
            for (int i = 0; i < 8; ++i) v[i] = ls[row][colb + i];
            if (mat == 0) {
                const size_t gbase = (size_t)(rowbase + row) * ldo0 + colb;
                if constexpr (sizeof(OT0) == 2) {
                    bf16x8 s;
                    #pragma unroll
                    for (int i = 0; i < 8; ++i) s[i] = f2bf(v[i]);
                    *(bf16x8*)(out0 + gbase) = s;
                } else {
                    float4 lo = { v[0], v[1], v[2], v[3] }, hi = { v[4], v[5], v[6], v[7] };
                    *(float4*)(out0 + gbase) = lo;
                    *(float4*)(out0 + gbase + 4) = hi;
                }
            } else {
                const size_t gbase = (size_t)(rowbase + row) * ldo1 + colb;
                if constexpr (sizeof(OT1) == 2) {
                    bf16x8 s;
                    #pragma unroll
                    for (int i = 0; i < 8; ++i) s[i] = f2bf(v[i]);
                    *(bf16x8*)(out1 + gbase) = s;
                } else {
                    float4 lo = { v[0], v[1], v[2], v[3] }, hi = { v[4], v[5], v[6], v[7] };
                    *(float4*)(out1 + gbase) = lo;
                    *(float4*)(out1 + gbase + 4) = hi;
                }
            }
        }
    }
}

// ---------- CSR helpers (scatter stores src id directly) ----------
__global__ void hist_k(const int* __restrict__ dst, int E, int* __restrict__ cnt) {
    for (int e = blockIdx.x*blockDim.x + threadIdx.x; e < E; e += gridDim.x*blockDim.x)
        atomicAdd(&cnt[dst[e]], 1);
}
__global__ void __launch_bounds__(256)
exscan_k(const int* __restrict__ cnt, int n, int* __restrict__ offs, int* __restrict__ cur) {
    __shared__ int ps[256];
    const int tid = threadIdx.x;
    const int chunk = (n + 255) / 256;
    const int lo = tid * chunk;
    const int hi = min(lo + chunk, n);
    int s = 0;
    for (int i = lo; i < hi; ++i) s += cnt[i];
    ps[tid] = s;
    __syncthreads();
    for (int off = 1; off < 256; off <<= 1) {
        int v = (tid >= off) ? ps[tid - off] : 0;
        __syncthreads();
        ps[tid] += v;
        __syncthreads();
    }
    int run = (tid == 0) ? 0 : ps[tid - 1];
    for (int i = lo; i < hi; ++i) { offs[i] = run; cur[i] = run; run += cnt[i]; }
    if (tid == 255) offs[n] = ps[255];
}
__global__ void scatter_k(const int* __restrict__ src, const int* __restrict__ dst, int E,
                          int* __restrict__ cur, int* __restrict__ slist) {
    for (int e = blockIdx.x*blockDim.x + threadIdx.x; e < E; e += gridDim.x*blockDim.x) {
        int pos = atomicAdd(&cur[dst[e]], 1);
        slist[pos] = src[e];
    }
}

// ---------- fused layer-1 attention: online softmax + beta gate + BN + ELU ----------
// 4 waves/block, one dst node per wave; lane owns 4 channels; kv interleaved [k(256)|v(256)]
__global__ void __launch_bounds__(256)
attn1_k(const int* __restrict__ offs, const int* __restrict__ slist,
        const short* __restrict__ qb, const short* __restrict__ kv,
        const float* __restrict__ xr, const float* __restrict__ wb,
        const float* __restrict__ g, const float* __restrict__ bbn,
        const float* __restrict__ mean, const float* __restrict__ var,
        short* __restrict__ hb)
{
    const int n = blockIdx.x * 4 + (threadIdx.x >> 6);
    const int lane = threadIdx.x & 63;
    const int c0 = lane * 4;
    const int lo = offs[n], hi = offs[n+1];
    const float4 q = ld4(qb + (size_t)n * HC1 + c0);
    const float scale = 0.088388347648318447f;   // 1/sqrt(128)

    float m = -INFINITY, s = 0.f;
    float a0 = 0.f, a1 = 0.f, a2 = 0.f, a3 = 0.f;
    float4 kc, vc;
    if (lo < hi) {
        const short* rp = kv + (size_t)slist[lo] * (2*HC1) + c0;
        kc = ld4(rp); vc = ld4(rp + HC1);
    }
    for (int i = lo; i < hi; ++i) {
        float4 kn, vn;
        if (i + 1 < hi) {                          // prefetch next edge's rows
            const short* rp = kv + (size_t)slist[i + 1] * (2*HC1) + c0;
            kn = ld4(rp); vn = ld4(rp + HC1);
        }
        float part = q.x*kc.x + q.y*kc.y + q.z*kc.z + q.w*kc.w;
        #pragma unroll
        for (int off = 16; off >= 1; off >>= 1) part += __shfl_xor(part, off, 64);
        const float alpha = part * scale;          // per-head (32-lane group) value
        // one-exp online softmax: e = exp(-|alpha-m|)
        const float dm = alpha - m;
        const bool up = dm > 0.f;                  // first iter: dm=+inf -> up
        const float e = __expf(up ? -dm : dm);     // exp(-|dm|); exp(-inf)=0 first iter
        const float rs = up ? e : 1.f;
        const float pp = up ? 1.f : e;
        s  = s*rs + pp;
        a0 = a0*rs + pp*vc.x; a1 = a1*rs + pp*vc.y;
        a2 = a2*rs + pp*vc.z; a3 = a3*rs + pp*vc.w;
        if (up) m = alpha;
        kc = kn; vc = vn;
    }
    const float inv = (s > 0.f) ? 1.f/s : 0.f;
    const float att[4] = { a0*inv, a1*inv, a2*inv, a3*inv };

    // beta gate
    const float4 x4 = ld4(xr + (size_t)n * HC1 + c0);
    const float xx[4] = { x4.x, x4.y, x4.z, x4.w };
    float d = 0.f;
    #pragma unroll
    for (int j = 0; j < 4; ++j) {
        int c = c0 + j;
        d += att[j]*wb[c] + xx[j]*wb[HC1 + c] + (att[j]-xx[j])*wb[2*HC1 + c];
    }
    d = wave_red_sum(d);
    const float beta = 1.f / (1.f + __expf(-d));
    s16x4 hv4;
    #pragma unroll
    for (int j = 0; j < 4; ++j) {
        int c = c0 + j;
        float hv = beta*xx[j] + (1.f-beta)*att[j];
        hv = (hv - mean[c]) * rsqrtf(var[c] + 1e-5f) * g[c] + bbn[c];
        hv = hv > 0.f ? hv : expm1f(hv);
        hv4[j] = f2bf(hv);
    }
    *(s16x4*)(hb + (size_t)n * HC1 + c0) = hv4;
}

// ---------- fused layer-2 attention: online softmax + beta gate + strided out ----------
// 4 waves/block, one dst node per wave; lane owns 2 channels; kv interleaved [k(128)|v(128)]
__global__ void __launch_bounds__(256)
attn2_k(const int* __restrict__ offs, const int* __restrict__ slist,
        const short* __restrict__ qb, const short* __restrict__ kv,
        const float* __restrict__ xr, const float* __restrict__ wb,
        float* __restrict__ outp, int colofs)
{
    const int n = blockIdx.x * 4 + (threadIdx.x >> 6);
    const int lane = threadIdx.x & 63;
    const int c0 = lane * 2;
    const int lo = offs[n], hi = offs[n+1];
    const float2 q = ld2(qb + (size_t)n * HC2 + c0);
    const float scale = 0.088388347648318447f;   // 1/sqrt(128)

    float m = -INFINITY, s = 0.f;
    float a0 = 0.f, a1 = 0.f;
    float2 kc, vc;
    if (lo < hi) {
        const short* rp = kv + (size_t)slist[lo] * (2*HC2) + c0;
        kc = ld2(rp); vc = ld2(rp + HC2);
    }
    for (int i = lo; i < hi; ++i) {
        float2 kn, vn;
        if (i + 1 < hi) {
            const short* rp = kv + (size_t)slist[i + 1] * (2*HC2) + c0;
            kn = ld2(rp); vn = ld2(rp + HC2);
        }
        float part = q.x*kc.x + q.y*kc.y;
        #pragma unroll
        for (int off = 32; off >= 1; off >>= 1) part += __shfl_xor(part, off, 64);
        const float alpha = part * scale;
        const float dm = alpha - m;
        const bool up = dm > 0.f;
        const float e = __expf(up ? -dm : dm);
        const float rs = up ? e : 1.f;
        const float pp = up ? 1.f : e;
        s  = s*rs + pp;
        a0 = a0*rs + pp*vc.x; a1 = a1*rs + pp*vc.y;
        if (up) m = alpha;
        kc = kn; vc = vn;
    }
    const float inv = (s > 0.f) ? 1.f/s : 0.f;
    const float att0 = a0*inv, att1 = a1*inv;

    const float2 x2 = ld2(xr + (size_t)n * HC2 + c0);
    float d = att0*wb[c0] + att1*wb[c0+1]
            + x2.x*wb[HC2+c0] + x2.y*wb[HC2+c0+1]
            + (att0-x2.x)*wb[2*HC2+c0] + (att1-x2.y)*wb[2*HC2+c0+1];
    d = wave_red_sum(d);
    const float beta = 1.f/(1.f+__expf(-d));
    outp[(size_t)n*(RR*HC2) + colofs + c0]     = beta*x2.x + (1.f-beta)*att0;
    outp[(size_t)n*(RR*HC2) + colofs + c0 + 1] = beta*x2.y + (1.f-beta)*att1;
}

extern "C" void kernel_launch(void* const* d_in, const int* in_sizes, int n_in,
                              void* d_out, int out_size, void* d_ws, size_t ws_size,
                              hipStream_t stream)
{
    const float* features = (const float*)d_in[0];
    const int*   n_ids    = (const int*)d_in[1];
    const int*   ei1      = (const int*)d_in[2];
    const int*   ei2      = (const int*)d_in[3];
    const float* wq1 = (const float*)d_in[4];  const float* bq1 = (const float*)d_in[5];
    const float* wk1 = (const float*)d_in[6];  const float* bk1 = (const float*)d_in[7];
    const float* wv1 = (const float*)d_in[8];  const float* bv1 = (const float*)d_in[9];
    const float* ws1 = (const float*)d_in[10]; const float* bs1 = (const float*)d_in[11];
    const float* wbeta1 = (const float*)d_in[12];
    const float* bn_g = (const float*)d_in[13]; const float* bn_b = (const float*)d_in[14];
    const float* bn_m = (const float*)d_in[15]; const float* bn_v = (const float*)d_in[16];
    const float* wq2 = (const float*)d_in[17]; const float* bq2 = (const float*)d_in[18];
    const float* wk2 = (const float*)d_in[19]; const float* bk2 = (const float*)d_in[20];
    const float* wv2 = (const float*)d_in[21]; const float* bv2 = (const float*)d_in[22];
    const float* ws2 = (const float*)d_in[23]; const float* bs2 = (const float*)d_in[24];
    const float* wbeta2 = (const float*)d_in[25];
    float* outp = (float*)d_out;

    char* p = (char*)d_ws;
    auto alloc = [&](size_t bytes) { char* q = p; p += (bytes + 255) & ~(size_t)255; return q; };
    short* kv1  = (short*)alloc(sizeof(short)*(size_t)NN0*2*HC1);  // 82 MB, [k|v] per row
    short* q1b  = (short*)alloc(sizeof(short)*(size_t)NN1*HC1);    // 10.2 MB
    float* xr1  = (float*)alloc(sizeof(float)*(size_t)NN1*HC1);    // 20.5 MB
    short* hbf  = (short*)alloc(sizeof(short)*(size_t)NN1*HC1);    // 10.2 MB
    short* xbf  = (short*)alloc(sizeof(short)*(size_t)NTOT*FIN);   // 25.6 MB
    short* wt1  = (short*)alloc(sizeof(short)*(size_t)RR*4*FIN*HC1);
    short* wt2  = (short*)alloc(sizeof(short)*(size_t)RR*4*HC1*HC2);
    short* kv2  = (short*)alloc(sizeof(short)*(size_t)NN1*2*HC2);  // 10.2 MB
    short* q2b  = (short*)alloc(sizeof(short)*(size_t)NB*HC2);
    float* xr2  = (float*)alloc(sizeof(float)*(size_t)NB*HC2);
    int* cnt1   = (int*)alloc(sizeof(int)*NN1);
    int* offs1  = (int*)alloc(sizeof(int)*(NN1+1));
    int* cur1   = (int*)alloc(sizeof(int)*NN1);
    int* slist1 = (int*)alloc(sizeof(int)*NE1);
    int* cnt2   = (int*)alloc(sizeof(int)*NB);
    int* offs2  = (int*)alloc(sizeof(int)*(NB+1));
    int* cur2   = (int*)alloc(sizeof(int)*NB);
    int* slist2 = (int*)alloc(sizeof(int)*NE2);
    (void)ws_size; (void)in_sizes; (void)n_in; (void)out_size;

    // ---- prologue: dtype conversions + fragment packing (once per launch) ----
    fcvt_k<<<(NTOT*FIN/4 + 255)/256, 256, 0, stream>>>(features, xbf, NTOT*FIN/4);
    {
        dim3 g1(128, 4, RR);
        wpack_k<FIN, HC1><<<g1, 256, 0, stream>>>(wq1, wk1, wv1, ws1, wt1);
        dim3 g2(128, 4, RR);
        wpack_k<HC1, HC2><<<g2, 256, 0, stream>>>(wq2, wk2, wv2, ws2, wt2);
    }
    const size_t WSZ = (size_t)FIN*HC1;

    for (int r = 0; r < RR; ++r) {
        const int* nid  = n_ids + (size_t)r*NN0;
        const int* src1 = ei1 + (size_t)r*2*NE1;
        const int* dst1 = src1 + NE1;
        const int* src2 = ei2 + (size_t)r*2*NE2;
        const int* dst2 = src2 + NE2;
        const short* ptq1 = wt1 + ((size_t)r*4 + 0)*WSZ;
        const short* ptk1 = wt1 + ((size_t)r*4 + 1)*WSZ;
        const short* ptv1 = wt1 + ((size_t)r*4 + 2)*WSZ;
        const short* pts1 = wt1 + ((size_t)r*4 + 3)*WSZ;
        const short* ptq2 = wt2 + ((size_t)r*4 + 0)*WSZ;
        const short* ptk2 = wt2 + ((size_t)r*4 + 1)*WSZ;
        const short* ptv2 = wt2 + ((size_t)r*4 + 2)*WSZ;
        const short* pts2 = wt2 + ((size_t)r*4 + 3)*WSZ;

        // ---- layer 1 CSR ----
        hipMemsetAsync(cnt1, 0, sizeof(int)*NN1, stream);
        hist_k<<<512, 256, 0, stream>>>(dst1, NE1, cnt1);
        exscan_k<<<1, 256, 0, stream>>>(cnt1, NN1, offs1, cur1);
        scatter_k<<<512, 256, 0, stream>>>(src1, dst1, NE1, cur1, slist1);

        // ---- layer 1 projections (MFMA, fused gather; k|v interleaved rows) ----
        gemm2l<FIN, HC1, short, short><<<NN0/32, 256, 0, stream>>>(
            xbf, FIN, nid, ptk1, bk1 + r*HC1, kv1, 2*HC1, ptv1, bv1 + r*HC1, kv1 + HC1, 2*HC1);
        gemm2l<FIN, HC1, short, float><<<NN1/32, 256, 0, stream>>>(
            xbf, FIN, nid, ptq1, bq1 + r*HC1, q1b, HC1, pts1, bs1 + r*HC1, xr1, HC1);

        // ---- layer 1 fused attention + epilogue ----
        attn1_k<<<NN1/4, 256, 0, stream>>>(offs1, slist1, q1b, kv1, xr1,
            wbeta1 + (size_t)r*3*HC1,
            bn_g + (size_t)r*HC1, bn_b + (size_t)r*HC1,
            bn_m + (size_t)r*HC1, bn_v + (size_t)r*HC1, hbf);

        // ---- layer 2 CSR ----
        hipMemsetAsync(cnt2, 0, sizeof(int)*NB, stream);
        hist_k<<<256, 256, 0, stream>>>(dst2, NE2, cnt2);
        exscan_k<<<1, 256, 0, stream>>>(cnt2, NB, offs2, cur2);
        scatter_k<<<256, 256, 0, stream>>>(src2, dst2, NE2, cur2, slist2);

        // ---- layer 2 projections (MFMA; k|v interleaved rows) ----
        gemm2l<HC1, HC2, short, short><<<NN1/32, 256, 0, stream>>>(
            hbf, HC1, nullptr, ptk2, bk2 + r*HC2, kv2, 2*HC2, ptv2, bv2 + r*HC2, kv2 + HC2, 2*HC2);
        gemm2l<HC1, HC2, short, float><<<NB/32, 256, 0, stream>>>(
            hbf, HC1, nullptr, ptq2, bq2 + r*HC2, q2b, HC2, pts2, bs2 + r*HC2, xr2, HC2);

        // ---- layer 2 fused attention + output ----
        attn2_k<<<NB/4, 256, 0, stream>>>(offs2, slist2, q2b, kv2, xr2,
            wbeta2 + (size_t)r*3*HC2, outp, r*HC2);
    }
}

// Round 7
// 764.374 us; speedup vs baseline: 1.0692x; 1.0692x over previous
//
#include <hip/hip_runtime.h>
#include <math.h>

#define RR 3
#define NTOT 100000
#define NN0 80000
#define NN1 20000
#define NB 4096
#define NE1 300000
#define NE2 65536
#define FIN 128
#define HC1 256   // layer1: 2 heads x 128
#define HC2 128   // layer2: 1 head x 128

typedef __attribute__((ext_vector_type(8))) short bf16x8;
typedef __attribute__((ext_vector_type(4))) short s16x4;
typedef __attribute__((ext_vector_type(2))) short s16x2;
typedef __attribute__((ext_vector_type(4))) float f32x4;

__device__ __forceinline__ float wave_red_sum(float v) {
    #pragma unroll
    for (int off = 32; off >= 1; off >>= 1) v += __shfl_xor(v, off, 64);
    return v;
}

__device__ __forceinline__ short f2bf(float x) {
    union { float f; unsigned u; } c; c.f = x;
    unsigned r = c.u + 0x7fffu + ((c.u >> 16) & 1u);
    return (short)(r >> 16);
}
__device__ __forceinline__ float bf2f(short s) {
    union { unsigned u; float f; } c; c.u = ((unsigned)(unsigned short)s) << 16;
    return c.f;
}

__device__ __forceinline__ float4 ld4(const float* p) { return *(const float4*)p; }
__device__ __forceinline__ float4 ld4(const short* p) {
    s16x4 v = *(const s16x4*)p;
    float4 r = { bf2f(v[0]), bf2f(v[1]), bf2f(v[2]), bf2f(v[3]) };
    return r;
}
__device__ __forceinline__ float2 ld2(const float* p) { return *(const float2*)p; }
__device__ __forceinline__ float2 ld2(const short* p) {
    s16x2 v = *(const s16x2*)p;
    float2 r = { bf2f(v[0]), bf2f(v[1]) };
    return r;
}

// ---------- convert features f32 -> bf16 ----------
__global__ void __launch_bounds__(256)
fcvt_k(const float* __restrict__ f, short* __restrict__ o, int n4) {
    int i = blockIdx.x * 256 + threadIdx.x;
    if (i < n4) {
        float4 v = *(const float4*)(f + (size_t)i * 4);
        s16x4 s = { f2bf(v.x), f2bf(v.y), f2bf(v.z), f2bf(v.w) };
        *(s16x4*)(o + (size_t)i * 4) = s;
    }
}

// ---------- pack 4 weight mats per replica into MFMA B-fragment order ----------
template<int K, int N>
__global__ void __launch_bounds__(256)
wpack_k(const float* __restrict__ W0, const float* __restrict__ W1,
        const float* __restrict__ W2, const float* __restrict__ W3,
        short* __restrict__ P) {
    constexpr int KS = K / 32;
    const int m = blockIdx.y, r = blockIdx.z;
    const float* W = (m == 0 ? W0 : m == 1 ? W1 : m == 2 ? W2 : W3) + (size_t)r * K * N;
    short* o = P + ((size_t)(r * 4 + m)) * K * N;
    for (int i = blockIdx.x * 256 + threadIdx.x; i < K * N; i += gridDim.x * 256) {
        int j = i & 7, lane = (i >> 3) & 63, f = i >> 9;
        int ks = f % KS, nt = f / KS;
        int k = ks * 32 + (lane >> 4) * 8 + j;
        int n = nt * 16 + (lane & 15);
        o[i] = f2bf(W[(size_t)k * N + n]);
    }
}

// ---------- MFMA GEMM, low-pressure tiling; per-output row stride (ldo) ----------
template<int K, int N, typename OT0, typename OT1>
__global__ void __launch_bounds__(256)
gemm2l(const short* __restrict__ xbf, int ldx, const int* __restrict__ gidx,
       const short* __restrict__ P0, const float* __restrict__ b0, OT0* __restrict__ out0, int ldo0,
       const short* __restrict__ P1, const float* __restrict__ b1, OT1* __restrict__ out1, int ldo1)
{
    constexpr int NT = N / 16;
    constexpr int NW = NT / 4;
    constexpr int KS = K / 32;
    constexpr int MT = 2;
    const int lane = threadIdx.x & 63;
    const int wid  = threadIdx.x >> 6;
    const int rowbase = blockIdx.x * (MT * 16);

    const short* ap[MT];
    #pragma unroll
    for (int mt = 0; mt < MT; ++mt) {
        int arow = rowbase + mt * 16 + (lane & 15);
        int srow = gidx ? gidx[arow] : arow;
        ap[mt] = xbf + (size_t)srow * ldx + ((lane >> 4) * 8);
    }
    const int fb = lane * 8;

    f32x4 acc[MT][NW][2];
    #pragma unroll
    for (int mt = 0; mt < MT; ++mt)
        #pragma unroll
        for (int j = 0; j < NW; ++j) { acc[mt][j][0] = (f32x4)(0.0f); acc[mt][j][1] = (f32x4)(0.0f); }

    for (int ks = 0; ks < KS; ++ks) {
        bf16x8 a[MT];
        #pragma unroll
        for (int mt = 0; mt < MT; ++mt) a[mt] = *(const bf16x8*)(ap[mt] + ks * 32);
        #pragma unroll
        for (int j = 0; j < NW; ++j) {
            const int nt = wid * NW + j;
            const int off = ((nt * KS + ks) << 9) + fb;
            bf16x8 bv0 = *(const bf16x8*)(P0 + off);
            bf16x8 bv1 = *(const bf16x8*)(P1 + off);
            #pragma unroll
            for (int mt = 0; mt < MT; ++mt) {
                acc[mt][j][0] = __builtin_amdgcn_mfma_f32_16x16x32_bf16(a[mt], bv0, acc[mt][j][0], 0, 0, 0);
                acc[mt][j][1] = __builtin_amdgcn_mfma_f32_16x16x32_bf16(a[mt], bv1, acc[mt][j][1], 0, 0, 0);
            }
        }
    }

    __shared__ float ls[MT * 16][N + 4];
    constexpr int CPT = (MT * 16) * N / 8 / 256;
    const int tid = threadIdx.x;

    #pragma unroll
    for (int mat = 0; mat < 2; ++mat) {
        if (mat) __syncthreads();
        const float* bias = mat ? b1 : b0;
        #pragma unroll
        for (int j = 0; j < NW; ++j) {
            const int nt = wid * NW + j;
            const float bb = bias[nt * 16 + (lane & 15)];
            #pragma unroll
            for (int mt = 0; mt < MT; ++mt)
                #pragma unroll
                for (int rg = 0; rg < 4; ++rg)
                    ls[mt * 16 + (lane >> 4) * 4 + rg][nt * 16 + (lane & 15)] =
                        acc[mt][j][mat][rg] + bb;
        }
        __syncthreads();
        #pragma unroll
        for (int c2 = 0; c2 < CPT; ++c2) {
            const int chunk = c2 * 256 + tid;
            const int row = chunk / (N / 8);
            const int colb = (chunk % (N / 8)) * 8;
            float v[8];
            #pragma unroll
            for (int i = 0; i < 8; ++i) v[i] = ls[row][colb + i];
            if (mat == 0) {
                const size_t gbase = (size_t)(rowbase + row) * ldo0 + colb;
                if constexpr (sizeof(OT0) == 2) {
                    bf16x8 s;
                    #pragma unroll
                    for (int i = 0; i < 8; ++i) s[i] = f2bf(v[i]);
                    *(bf16x8*)(out0 + gbase) = s;
                } else {
                    float4 lo = { v[0], v[1], v[2], v[3] }, hi = { v[4], v[5], v[6], v[7] };
                    *(float4*)(out0 + gbase) = lo;
                    *(float4*)(out0 + gbase + 4) = hi;
                }
            } else {
                const size_t gbase = (size_t)(rowbase + row) * ldo1 + colb;
                if constexpr (sizeof(OT1) == 2) {
                    bf16x8 s;
                    #pragma unroll
                    for (int i = 0; i < 8; ++i) s[i] = f2bf(v[i]);
                    *(bf16x8*)(out1 + gbase) = s;
                } else {
                    float4 lo = { v[0], v[1], v[2], v[3] }, hi = { v[4], v[5], v[6], v[7] };
                    *(float4*)(out1 + gbase) = lo;
                    *(float4*)(out1 + gbase + 4) = hi;
                }
            }
        }
    }
}

// ---------- CSR helpers (scatter stores src id directly) ----------
__global__ void hist_k(const int* __restrict__ dst, int E, int* __restrict__ cnt) {
    for (int e = blockIdx.x*blockDim.x + threadIdx.x; e < E; e += gridDim.x*blockDim.x)
        atomicAdd(&cnt[dst[e]], 1);
}
__global__ void __launch_bounds__(256)
exscan_k(const int* __restrict__ cnt, int n, int* __restrict__ offs, int* __restrict__ cur) {
    __shared__ int ps[256];
    const int tid = threadIdx.x;
    const int chunk = (n + 255) / 256;
    const int lo = tid * chunk;
    const int hi = min(lo + chunk, n);
    int s = 0;
    for (int i = lo; i < hi; ++i) s += cnt[i];
    ps[tid] = s;
    __syncthreads();
    for (int off = 1; off < 256; off <<= 1) {
        int v = (tid >= off) ? ps[tid - off] : 0;
        __syncthreads();
        ps[tid] += v;
        __syncthreads();
    }
    int run = (tid == 0) ? 0 : ps[tid - 1];
    for (int i = lo; i < hi; ++i) { offs[i] = run; cur[i] = run; run += cnt[i]; }
    if (tid == 255) offs[n] = ps[255];
}
__global__ void scatter_k(const int* __restrict__ src, const int* __restrict__ dst, int E,
                          int* __restrict__ cur, int* __restrict__ slist) {
    for (int e = blockIdx.x*blockDim.x + threadIdx.x; e < E; e += gridDim.x*blockDim.x) {
        int pos = atomicAdd(&cur[dst[e]], 1);
        slist[pos] = src[e];
    }
}

// ---------- fused layer-1 attention, edge-PAIR pipelined ----------
// one wave per dst node; lane owns 4 channels (lanes 0-31 head0, 32-63 head1)
__global__ void __launch_bounds__(64)
attn1_k(const int* __restrict__ offs, const int* __restrict__ slist,
        const short* __restrict__ qb, const short* __restrict__ kb, const short* __restrict__ vb,
        const float* __restrict__ xr, const float* __restrict__ wb,
        const float* __restrict__ g, const float* __restrict__ bbn,
        const float* __restrict__ mean, const float* __restrict__ var,
        short* __restrict__ hb)
{
    const int n = blockIdx.x;
    const int lane = threadIdx.x;
    const int c0 = lane * 4;
    const int lo = offs[n], hi = offs[n+1];
    const float4 q = ld4(qb + (size_t)n * HC1 + c0);
    const float scale = 0.088388347648318447f;   // 1/sqrt(128)

    float m = -INFINITY, s = 0.f;
    float a0 = 0.f, a1 = 0.f, a2 = 0.f, a3 = 0.f;
    float4 k0 = {0,0,0,0}, v0 = {0,0,0,0}, k1 = {0,0,0,0}, v1 = {0,0,0,0};
    if (lo < hi) {
        int sr = slist[lo];
        k0 = ld4(kb + (size_t)sr * HC1 + c0); v0 = ld4(vb + (size_t)sr * HC1 + c0);
    }
    if (lo + 1 < hi) {
        int sr = slist[lo + 1];
        k1 = ld4(kb + (size_t)sr * HC1 + c0); v1 = ld4(vb + (size_t)sr * HC1 + c0);
    }
    for (int i = lo; i < hi; i += 2) {
        float4 kn0 = {0,0,0,0}, vn0 = {0,0,0,0}, kn1 = {0,0,0,0}, vn1 = {0,0,0,0};
        if (i + 2 < hi) {                         // prefetch next pair (2KB in flight)
            int sr = slist[i + 2];
            kn0 = ld4(kb + (size_t)sr * HC1 + c0); vn0 = ld4(vb + (size_t)sr * HC1 + c0);
        }
        if (i + 3 < hi) {
            int sr = slist[i + 3];
            kn1 = ld4(kb + (size_t)sr * HC1 + c0); vn1 = ld4(vb + (size_t)sr * HC1 + c0);
        }
        float p0 = q.x*k0.x + q.y*k0.y + q.z*k0.z + q.w*k0.w;
        float p1 = q.x*k1.x + q.y*k1.y + q.z*k1.z + q.w*k1.w;
        #pragma unroll
        for (int off = 16; off >= 1; off >>= 1) {   // two independent reduce chains
            p0 += __shfl_xor(p0, off, 64);
            p1 += __shfl_xor(p1, off, 64);
        }
        const float alpha0 = p0 * scale;
        const float alpha1 = (i + 1 < hi) ? p1 * scale : -INFINITY;
        // update edge 0 (alpha0 always finite here)
        float mn = fmaxf(m, alpha0);
        float rs = __expf(m - mn);                 // m=-inf first iter -> 0
        float pp = __expf(alpha0 - mn);
        s  = s*rs + pp;
        a0 = a0*rs + pp*v0.x; a1 = a1*rs + pp*v0.y;
        a2 = a2*rs + pp*v0.z; a3 = a3*rs + pp*v0.w;
        m = mn;
        // update edge 1 (alpha1=-inf when absent -> rs=1, pp=0: exact no-op)
        mn = fmaxf(m, alpha1);
        rs = __expf(m - mn);
        pp = __expf(alpha1 - mn);
        s  = s*rs + pp;
        a0 = a0*rs + pp*v1.x; a1 = a1*rs + pp*v1.y;
        a2 = a2*rs + pp*v1.z; a3 = a3*rs + pp*v1.w;
        m = mn;
        k0 = kn0; v0 = vn0; k1 = kn1; v1 = vn1;
    }
    const float inv = (s > 0.f) ? 1.f/s : 0.f;
    const float att[4] = { a0*inv, a1*inv, a2*inv, a3*inv };

    // beta gate
    const float4 x4 = ld4(xr + (size_t)n * HC1 + c0);
    const float xx[4] = { x4.x, x4.y, x4.z, x4.w };
    float d = 0.f;
    #pragma unroll
    for (int j = 0; j < 4; ++j) {
        int c = c0 + j;
        d += att[j]*wb[c] + xx[j]*wb[HC1 + c] + (att[j]-xx[j])*wb[2*HC1 + c];
    }
    d = wave_red_sum(d);
    const float beta = 1.f / (1.f + __expf(-d));
    s16x4 hv4;
    #pragma unroll
    for (int j = 0; j < 4; ++j) {
        int c = c0 + j;
        float hv = beta*xx[j] + (1.f-beta)*att[j];
        hv = (hv - mean[c]) * rsqrtf(var[c] + 1e-5f) * g[c] + bbn[c];
        hv = hv > 0.f ? hv : expm1f(hv);
        hv4[j] = f2bf(hv);
    }
    *(s16x4*)(hb + (size_t)n * HC1 + c0) = hv4;
}

// ---------- fused layer-2 attention, edge-PAIR pipelined ----------
// one wave per dst node; lane owns 2 channels; single head -> full-64-lane dot
__global__ void __launch_bounds__(64)
attn2_k(const int* __restrict__ offs, const int* __restrict__ slist,
        const short* __restrict__ qb, const short* __restrict__ kb, const short* __restrict__ vb,
        const float* __restrict__ xr, const float* __restrict__ wb,
        float* __restrict__ outp, int colofs)
{
    const int n = blockIdx.x;
    const int lane = threadIdx.x;
    const int c0 = lane * 2;
    const int lo = offs[n], hi = offs[n+1];
    const float2 q = ld2(qb + (size_t)n * HC2 + c0);
    const float scale = 0.088388347648318447f;   // 1/sqrt(128)

    float m = -INFINITY, s = 0.f;
    float a0 = 0.f, a1 = 0.f;
    float2 k0 = {0,0}, v0 = {0,0}, k1 = {0,0}, v1 = {0,0};
    if (lo < hi) {
        int sr = slist[lo];
        k0 = ld2(kb + (size_t)sr * HC2 + c0); v0 = ld2(vb + (size_t)sr * HC2 + c0);
    }
    if (lo + 1 < hi) {
        int sr = slist[lo + 1];
        k1 = ld2(kb + (size_t)sr * HC2 + c0); v1 = ld2(vb + (size_t)sr * HC2 + c0);
    }
    for (int i = lo; i < hi; i += 2) {
        float2 kn0 = {0,0}, vn0 = {0,0}, kn1 = {0,0}, vn1 = {0,0};
        if (i + 2 < hi) {
            int sr = slist[i + 2];
            kn0 = ld2(kb + (size_t)sr * HC2 + c0); vn0 = ld2(vb + (size_t)sr * HC2 + c0);
        }
        if (i + 3 < hi) {
            int sr = slist[i + 3];
            kn1 = ld2(kb + (size_t)sr * HC2 + c0); vn1 = ld2(vb + (size_t)sr * HC2 + c0);
        }
        float p0 = q.x*k0.x + q.y*k0.y;
        float p1 = q.x*k1.x + q.y*k1.y;
        #pragma unroll
        for (int off = 32; off >= 1; off >>= 1) {
            p0 += __shfl_xor(p0, off, 64);
            p1 += __shfl_xor(p1, off, 64);
        }
        const float alpha0 = p0 * scale;
        const float alpha1 = (i + 1 < hi) ? p1 * scale : -INFINITY;
        float mn = fmaxf(m, alpha0);
        float rs = __expf(m - mn);
        float pp = __expf(alpha0 - mn);
        s  = s*rs + pp;
        a0 = a0*rs + pp*v0.x; a1 = a1*rs + pp*v0.y;
        m = mn;
        mn = fmaxf(m, alpha1);
        rs = __expf(m - mn);
        pp = __expf(alpha1 - mn);
        s  = s*rs + pp;
        a0 = a0*rs + pp*v1.x; a1 = a1*rs + pp*v1.y;
        m = mn;
        k0 = kn0; v0 = vn0; k1 = kn1; v1 = vn1;
    }
    const float inv = (s > 0.f) ? 1.f/s : 0.f;
    const float att0 = a0*inv, att1 = a1*inv;

    const float2 x2 = ld2(xr + (size_t)n * HC2 + c0);
    float d = att0*wb[c0] + att1*wb[c0+1]
            + x2.x*wb[HC2+c0] + x2.y*wb[HC2+c0+1]
            + (att0-x2.x)*wb[2*HC2+c0] + (att1-x2.y)*wb[2*HC2+c0+1];
    d = wave_red_sum(d);
    const float beta = 1.f/(1.f+__expf(-d));
    outp[(size_t)n*(RR*HC2) + colofs + c0]     = beta*x2.x + (1.f-beta)*att0;
    outp[(size_t)n*(RR*HC2) + colofs + c0 + 1] = beta*x2.y + (1.f-beta)*att1;
}

extern "C" void kernel_launch(void* const* d_in, const int* in_sizes, int n_in,
                              void* d_out, int out_size, void* d_ws, size_t ws_size,
                              hipStream_t stream)
{
    const float* features = (const float*)d_in[0];
    const int*   n_ids    = (const int*)d_in[1];
    const int*   ei1      = (const int*)d_in[2];
    const int*   ei2      = (const int*)d_in[3];
    const float* wq1 = (const float*)d_in[4];  const float* bq1 = (const float*)d_in[5];
    const float* wk1 = (const float*)d_in[6];  const float* bk1 = (const float*)d_in[7];
    const float* wv1 = (const float*)d_in[8];  const float* bv1 = (const float*)d_in[9];
    const float* ws1 = (const float*)d_in[10]; const float* bs1 = (const float*)d_in[11];
    const float* wbeta1 = (const float*)d_in[12];
    const float* bn_g = (const float*)d_in[13]; const float* bn_b = (const float*)d_in[14];
    const float* bn_m = (const float*)d_in[15]; const float* bn_v = (const float*)d_in[16];
    const float* wq2 = (const float*)d_in[17]; const float* bq2 = (const float*)d_in[18];
    const float* wk2 = (const float*)d_in[19]; const float* bk2 = (const float*)d_in[20];
    const float* wv2 = (const float*)d_in[21]; const float* bv2 = (const float*)d_in[22];
    const float* ws2 = (const float*)d_in[23]; const float* bs2 = (const float*)d_in[24];
    const float* wbeta2 = (const float*)d_in[25];
    float* outp = (float*)d_out;

    char* p = (char*)d_ws;
    auto alloc = [&](size_t bytes) { char* q = p; p += (bytes + 255) & ~(size_t)255; return q; };
    short* k1b  = (short*)alloc(sizeof(short)*(size_t)NN0*HC1);   // 41 MB
    short* v1b  = (short*)alloc(sizeof(short)*(size_t)NN0*HC1);   // 41 MB
    short* q1b  = (short*)alloc(sizeof(short)*(size_t)NN1*HC1);   // 10.2 MB
    float* xr1  = (float*)alloc(sizeof(float)*(size_t)NN1*HC1);   // 20.5 MB
    short* hbf  = (short*)alloc(sizeof(short)*(size_t)NN1*HC1);   // 10.2 MB
    short* xbf  = (short*)alloc(sizeof(short)*(size_t)NTOT*FIN);  // 25.6 MB
    short* wt1  = (short*)alloc(sizeof(short)*(size_t)RR*4*FIN*HC1);
    short* wt2  = (short*)alloc(sizeof(short)*(size_t)RR*4*HC1*HC2);
    short* k2b  = (short*)alloc(sizeof(short)*(size_t)NN1*HC2);
    short* v2b  = (short*)alloc(sizeof(short)*(size_t)NN1*HC2);
    short* q2b  = (short*)alloc(sizeof(short)*(size_t)NB*HC2);
    float* xr2  = (float*)alloc(sizeof(float)*(size_t)NB*HC2);
    int* cnt1   = (int*)alloc(sizeof(int)*NN1);
    int* offs1  = (int*)alloc(sizeof(int)*(NN1+1));
    int* cur1   = (int*)alloc(sizeof(int)*NN1);
    int* slist1 = (int*)alloc(sizeof(int)*NE1);
    int* cnt2   = (int*)alloc(sizeof(int)*NB);
    int* offs2  = (int*)alloc(sizeof(int)*(NB+1));
    int* cur2   = (int*)alloc(sizeof(int)*NB);
    int* slist2 = (int*)alloc(sizeof(int)*NE2);
    (void)ws_size; (void)in_sizes; (void)n_in; (void)out_size;

    // ---- prologue: dtype conversions + fragment packing (once per launch) ----
    fcvt_k<<<(NTOT*FIN/4 + 255)/256, 256, 0, stream>>>(features, xbf, NTOT*FIN/4);
    {
        dim3 g1(128, 4, RR);
        wpack_k<FIN, HC1><<<g1, 256, 0, stream>>>(wq1, wk1, wv1, ws1, wt1);
        dim3 g2(128, 4, RR);
        wpack_k<HC1, HC2><<<g2, 256, 0, stream>>>(wq2, wk2, wv2, ws2, wt2);
    }
    const size_t WSZ = (size_t)FIN*HC1;

    for (int r = 0; r < RR; ++r) {
        const int* nid  = n_ids + (size_t)r*NN0;
        const int* src1 = ei1 + (size_t)r*2*NE1;
        const int* dst1 = src1 + NE1;
        const int* src2 = ei2 + (size_t)r*2*NE2;
        const int* dst2 = src2 + NE2;
        const short* ptq1 = wt1 + ((size_t)r*4 + 0)*WSZ;
        const short* ptk1 = wt1 + ((size_t)r*4 + 1)*WSZ;
        const short* ptv1 = wt1 + ((size_t)r*4 + 2)*WSZ;
        const short* pts1 = wt1 + ((size_t)r*4 + 3)*WSZ;
        const short* ptq2 = wt2 + ((size_t)r*4 + 0)*WSZ;
        const short* ptk2 = wt2 + ((size_t)r*4 + 1)*WSZ;
        const short* ptv2 = wt2 + ((size_t)r*4 + 2)*WSZ;
        const short* pts2 = wt2 + ((size_t)r*4 + 3)*WSZ;

        // ---- layer 1 CSR ----
        hipMemsetAsync(cnt1, 0, sizeof(int)*NN1, stream);
        hist_k<<<512, 256, 0, stream>>>(dst1, NE1, cnt1);
        exscan_k<<<1, 256, 0, stream>>>(cnt1, NN1, offs1, cur1);
        scatter_k<<<512, 256, 0, stream>>>(src1, dst1, NE1, cur1, slist1);

        // ---- layer 1 projections (MFMA, fused gather, bf16 out) ----
        gemm2l<FIN, HC1, short, short><<<NN0/32, 256, 0, stream>>>(
            xbf, FIN, nid, ptk1, bk1 + r*HC1, k1b, HC1, ptv1, bv1 + r*HC1, v1b, HC1);
        gemm2l<FIN, HC1, short, float><<<NN1/32, 256, 0, stream>>>(
            xbf, FIN, nid, ptq1, bq1 + r*HC1, q1b, HC1, pts1, bs1 + r*HC1, xr1, HC1);

        // ---- layer 1 fused attention + epilogue ----
        attn1_k<<<NN1, 64, 0, stream>>>(offs1, slist1, q1b, k1b, v1b, xr1,
            wbeta1 + (size_t)r*3*HC1,
            bn_g + (size_t)r*HC1, bn_b + (size_t)r*HC1,
            bn_m + (size_t)r*HC1, bn_v + (size_t)r*HC1, hbf);

        // ---- layer 2 CSR ----
        hipMemsetAsync(cnt2, 0, sizeof(int)*NB, stream);
        hist_k<<<256, 256, 0, stream>>>(dst2, NE2, cnt2);
        exscan_k<<<1, 256, 0, stream>>>(cnt2, NB, offs2, cur2);
        scatter_k<<<256, 256, 0, stream>>>(src2, dst2, NE2, cur2, slist2);

        // ---- layer 2 projections (MFMA, bf16 out for k/v/q) ----
        gemm2l<HC1, HC2, short, short><<<NN1/32, 256, 0, stream>>>(
            hbf, HC1, nullptr, ptk2, bk2 + r*HC2, k2b, HC2, ptv2, bv2 + r*HC2, v2b, HC2);
        gemm2l<HC1, HC2, short, float><<<NB/32, 256, 0, stream>>>(
            hbf, HC1, nullptr, ptq2, bq2 + r*HC2, q2b, HC2, pts2, bs2 + r*HC2, xr2, HC2);

        // ---- layer 2 fused attention + output ----
        attn2_k<<<NB, 64, 0, stream>>>(offs2, slist2, q2b, k2b, v2b, xr2,
            wbeta2 + (size_t)r*3*HC2, outp, r*HC2);
    }
}